// Round 1
// 94.235 us; speedup vs baseline: 1.0209x; 1.0209x over previous
//
#include <hip/hip_runtime.h>

// DFMBPSROIAlign. R11 (= R10 + LDS bank-spread):
//  - Split the 32B/pixel slab (10ch + 6 pad ushorts) into TWO LDS arrays:
//      slabA[pix] = uint4  (ch0..7, 16B/pixel)  -> ds_read_b128
//      slabB[pix] = uint   (ch8..9,  4B/pixel)  -> ds_read_b32
//    With the old 32B stride, b128 start slots were confined to
//    addr%128 in {0,32,64,96} => only 16/32 banks, ~16 lanes per 4-bank
//    group at random ROI coords (~2x conflict cost). 16B stride puts the
//    start slot at pix&7 => random pixels cover all 32 banks; b32 lands
//    at bank pix%32 (2-way avg aliasing = free per m136).
//  - LDS 37KB -> 23.1KB, staging traffic -38%, pack buffer 1.81->1.13MB.
//  Structure otherwise proven R6-R10: pack ft->bf16, per-part LDS slab
//  gather with separable <=4x<=4 footprint, bf16-pair blocked ws, 64n-slab
//  transpose+unpack, NT stores. Harness poison floor ~47-56us of dur.

constexpr int C  = 10;
constexpr int PH = 7;
constexpr int PW = 7;
constexpr int H  = 34;
constexpr int W  = 34;
constexpr int P  = PH * PW;         // 49
constexpr int HW = H * W;           // 1156
constexpr int FT_C_STRIDE = P * HW; // 56644
constexpr int CPAD = 12;            // fp32 fallback pad
constexpr int R  = C * P;           // 490
constexpr int RU = (C / 2) * P;     // 245 uint rows (bf16 channel pairs)

typedef float vf2 __attribute__((ext_vector_type(2)));  // native vec for NT store

__device__ inline unsigned bf16rn(float f) {
    unsigned u = __float_as_uint(f);
    return (u + 0x7FFFu + ((u >> 16) & 1u)) >> 16;
}
__device__ inline float bf16lo(unsigned u) { return __uint_as_float(u << 16); }
__device__ inline float bf16hi(unsigned u) { return __uint_as_float(u & 0xFFFF0000u); }

// ---- pack ft (C,P,H,W) fp32 -> ftA[p][pix] uint4 (ch0..7) + ftBb[p][pix]
//      uint (ch8..9); grid (49,5) ----
__global__ __launch_bounds__(256) void dfmb_pack(
    const float* __restrict__ ft, uint4* __restrict__ ftA,
    unsigned* __restrict__ ftBb)
{
    const int p   = blockIdx.x;
    const int pix = blockIdx.y * 256 + threadIdx.x;
    if (pix >= HW) return;
    const float* __restrict__ src = ft + p * HW;
    unsigned d[5];
#pragma unroll
    for (int k = 0; k < 5; ++k) {
        float a = src[(2 * k) * FT_C_STRIDE + pix];
        float b = src[(2 * k + 1) * FT_C_STRIDE + pix];
        d[k] = bf16rn(a) | (bf16rn(b) << 16);
    }
    ftA[(size_t)p * HW + pix]  = make_uint4(d[0], d[1], d[2], d[3]);
    ftBb[(size_t)p * HW + pix] = d[4];
}

// ---- main: bf16 LDS slab gather (split A/B arrays), bf16-pair ws out ----
__global__ __launch_bounds__(512) void dfmb_main(
    const uint4* __restrict__ ftA,
    const unsigned* __restrict__ ftBb,
    const float* __restrict__ rois,
    unsigned* __restrict__ ws,  // [n/64][c2*49+p][n%64] bf16 pairs
    int N)
{
    __shared__ uint4 slabA[HW];                   // 18496 B, 16B/pixel
    __shared__ __align__(16) unsigned slabB[HW];  //  4624 B,  4B/pixel

    const int p  = blockIdx.y;
    const int ph = p / PW;
    const int pw = p - ph * PW;

    // Dense conflict-free staging: 1156 + 289 uint4 over 512 threads.
    {
        const uint4* __restrict__ sA = ftA + (size_t)p * HW;
        for (int i = threadIdx.x; i < HW; i += 512) slabA[i] = sA[i];
        const uint4* __restrict__ sB = (const uint4*)(ftBb + (size_t)p * HW);
        uint4* dB = (uint4*)slabB;
        for (int i = threadIdx.x; i < HW / 4; i += 512) dB[i] = sB[i];
    }
    __syncthreads();

    const int n = blockIdx.x * 512 + threadIdx.x;
    if (n >= N) return;

    // Coordinate setup — contraction OFF so floor() args match the reference
    // rounding (verified passing R0-R10).
    float wstart, hstart, sub_w, sub_h;
    {
#pragma clang fp contract(off)
        const float inv_stride = 0.0625f;
        float rsw = rois[n * 5 + 1] * inv_stride;
        float rsh = rois[n * 5 + 2] * inv_stride;
        float rew = rois[n * 5 + 3] * inv_stride;
        float reh = rois[n * 5 + 4] * inv_stride;
        float roi_h = reh - rsh; if (!(roi_h > 0.1f)) roi_h = 0.1f;
        float roi_w = rew - rsw; if (!(roi_w > 0.1f)) roi_w = 0.1f;
        float bin_h = roi_h / 7.0f;
        float bin_w = roi_w / 7.0f;
        sub_h = bin_h * 0.25f;
        sub_w = bin_w * 0.25f;
        hstart = floorf(rsh + (float)ph * bin_h);
        wstart = floorf(rsw + (float)pw * bin_w);
    }

    // ---- separable 1-D weight footprints (<=4 cols x <=4 rows) ----
    float Xw0 = 0.f, Xw1 = 0.f, Xw2 = 0.f, Xw3 = 0.f, cntx = 0.f;
    int xbase = 0;
#pragma unroll
    for (int iw = 0; iw < 4; ++iw) {
        float w;
        {
#pragma clang fp contract(off)
            w = wstart + ((float)iw + 0.5f) * sub_w;
        }
        float kw  = (w > -1.0f && w < 34.0f) ? 1.0f : 0.0f;
        float x1f = floorf(w), x2f = ceilf(w);
        float x1v = (x1f >= 0.0f && x1f < 34.0f) ? 1.0f : 0.0f;
        float x2v = (x2f >= 0.0f && x2f < 34.0f) ? 1.0f : 0.0f;
        int x1 = (int)fminf(fmaxf(x1f, 0.0f), 33.0f);
        int x2 = (int)fminf(fmaxf(x2f, 0.0f), 33.0f);
        float dx = w - (float)x1;           // vs CLAMPED corner (ref semantics)
        if (iw == 0) xbase = x1;            // minimal column (w monotone in iw)
        float a = kw * (1.0f - dx) * x1v;
        float b = kw * dx * x2v;
        int i1 = x1 - xbase, i2 = x2 - xbase;
        Xw0 += (i1 == 0) ? a : 0.f;  Xw1 += (i1 == 1) ? a : 0.f;
        Xw2 += (i1 == 2) ? a : 0.f;  Xw3 += (i1 == 3) ? a : 0.f;
        Xw0 += (i2 == 0) ? b : 0.f;  Xw1 += (i2 == 1) ? b : 0.f;
        Xw2 += (i2 == 2) ? b : 0.f;  Xw3 += (i2 == 3) ? b : 0.f;
        cntx += kw;
    }

    float Yw0 = 0.f, Yw1 = 0.f, Yw2 = 0.f, Yw3 = 0.f, cnty = 0.f;
    int ybase = 0;
#pragma unroll
    for (int ih = 0; ih < 4; ++ih) {
        float h;
        {
#pragma clang fp contract(off)
            h = hstart + ((float)ih + 0.5f) * sub_h;
        }
        float kh  = (h > -1.0f && h < 34.0f) ? 1.0f : 0.0f;
        float y1f = floorf(h), y2f = ceilf(h);
        float y1v = (y1f >= 0.0f && y1f < 34.0f) ? 1.0f : 0.0f;
        float y2v = (y2f >= 0.0f && y2f < 34.0f) ? 1.0f : 0.0f;
        int y1 = (int)fminf(fmaxf(y1f, 0.0f), 33.0f);
        int y2 = (int)fminf(fmaxf(y2f, 0.0f), 33.0f);
        float dy = h - (float)y1;
        if (ih == 0) ybase = y1;
        float a = kh * (1.0f - dy) * y1v;
        float b = kh * dy * y2v;
        int i1 = y1 - ybase, i2 = y2 - ybase;
        Yw0 += (i1 == 0) ? a : 0.f;  Yw1 += (i1 == 1) ? a : 0.f;
        Yw2 += (i1 == 2) ? a : 0.f;  Yw3 += (i1 == 3) ? a : 0.f;
        Yw0 += (i2 == 0) ? b : 0.f;  Yw1 += (i2 == 1) ? b : 0.f;
        Yw2 += (i2 == 2) ? b : 0.f;  Yw3 += (i2 == 3) ? b : 0.f;
        cnty += kh;
    }

    // ---- accumulate over footprint: b128 (ch0..7) + b32 (ch8..9) ----
    float s0=0.f,s1=0.f,s2=0.f,s3=0.f,s4=0.f,s5=0.f,s6=0.f,s7=0.f,s8=0.f,s9=0.f;
#pragma unroll
    for (int cy = 0; cy < 4; ++cy) {
        float wy = (cy == 0) ? Yw0 : (cy == 1) ? Yw1 : (cy == 2) ? Yw2 : Yw3;
        if (wy != 0.0f) {
            int yy = min(ybase + cy, 33);
            int rowoff = yy * W;
#pragma unroll
            for (int cx = 0; cx < 4; ++cx) {
                float wx = (cx == 0) ? Xw0 : (cx == 1) ? Xw1
                         : (cx == 2) ? Xw2 : Xw3;
                float wgt = wy * wx;
                if (wgt != 0.0f) {
                    int xx = min(xbase + cx, 33);
                    int pixi = rowoff + xx;
                    uint4 a = slabA[pixi];      // ch 0..7
                    unsigned b = slabB[pixi];   // ch 8..9
                    s0 += wgt * bf16lo(a.x);  s1 += wgt * bf16hi(a.x);
                    s2 += wgt * bf16lo(a.y);  s3 += wgt * bf16hi(a.y);
                    s4 += wgt * bf16lo(a.z);  s5 += wgt * bf16hi(a.z);
                    s6 += wgt * bf16lo(a.w);  s7 += wgt * bf16hi(a.w);
                    s8 += wgt * bf16lo(b);    s9 += wgt * bf16hi(b);
                }
            }
        }
    }

    float cnt = cntx * cnty;
    if (!(cnt > 0.0f)) cnt = 1.0f;
    float inv = 1.0f / cnt;

    // Pack 10 results into 5 bf16-pair uints; blocked coalesced stores.
    unsigned r01 = bf16rn(s0 * inv) | (bf16rn(s1 * inv) << 16);
    unsigned r23 = bf16rn(s2 * inv) | (bf16rn(s3 * inv) << 16);
    unsigned r45 = bf16rn(s4 * inv) | (bf16rn(s5 * inv) << 16);
    unsigned r67 = bf16rn(s6 * inv) | (bf16rn(s7 * inv) << 16);
    unsigned r89 = bf16rn(s8 * inv) | (bf16rn(s9 * inv) << 16);

    unsigned* __restrict__ o = ws + (size_t)(n >> 6) * (RU * 64)
                                  + (size_t)p * 64 + (n & 63);
    o[0 * (P * 64)] = r01;
    o[1 * (P * 64)] = r23;
    o[2 * (P * 64)] = r45;
    o[3 * (P * 64)] = r67;
    o[4 * (P * 64)] = r89;
}

// Per-64n-slab transpose+unpack: ws[nblk][c2*49+p][nl] (245x64 uints,
// contiguous 62.7KB) -> out[n][c*49+p] fp32, nontemporal vf2 stores.
__global__ __launch_bounds__(1024) void dfmb_phase2(
    const unsigned* __restrict__ ws, float* __restrict__ out, int N)
{
    __shared__ unsigned t[RU * 65];     // 63700 B
    const int nblk = blockIdx.x;
    const unsigned* __restrict__ srcb = ws + (size_t)nblk * (RU * 64);

    // Load 245 rows x 64 nl contiguous via uint4 (3920 of them).
    for (int i = threadIdx.x; i < RU * 16; i += 1024) {
        int rr  = i >> 4;
        int nl4 = (i & 15) * 4;
        uint4 v = ((const uint4*)srcb)[i];
        unsigned* tp = &t[rr * 65 + nl4];
        tp[0] = v.x; tp[1] = v.y; tp[2] = v.z; tp[3] = v.w;
    }
    __syncthreads();

    // Write out[n0+nl][2k..2k+1]: lane-consecutive k -> coalesced 512B vf2.
    const int n0 = nblk * 64;
    for (int j = threadIdx.x; j < 64 * (R / 2); j += 1024) {
        int nl = j / (R / 2);
        int k  = j - nl * (R / 2);
        int r0 = 2 * k, r1 = 2 * k + 1;
        int c0 = r0 / P, p0 = r0 - c0 * P;
        int c1 = r1 / P, p1 = r1 - c1 * P;
        unsigned u0 = t[((c0 >> 1) * P + p0) * 65 + nl];
        unsigned u1 = t[((c1 >> 1) * P + p1) * 65 + nl];
        vf2 v;
        v.x = (c0 & 1) ? bf16hi(u0) : bf16lo(u0);
        v.y = (c1 & 1) ? bf16hi(u1) : bf16lo(u1);
        __builtin_nontemporal_store(v, (vf2*)(out + (size_t)(n0 + nl) * R) + k);
    }
}

// ---- fallback (no ws): fp32 LDS-slab kernel, direct strided writes ----
__global__ __launch_bounds__(512, 4) void dfmb_phase1_direct(
    const float* __restrict__ ft,
    const float* __restrict__ rois,
    float* __restrict__ dst,
    int N)
{
    __shared__ float tile[HW * CPAD];
    const int p  = blockIdx.y;
    const int ph = p / PW;
    const int pw = p - ph * PW;
    const float* __restrict__ src = ft + p * HW;
    for (int i = threadIdx.x; i < C * HW; i += 512) {
        int c = i / HW;
        int r = i - c * HW;
        tile[r * CPAD + c] = src[c * FT_C_STRIDE + r];
    }
    __syncthreads();
    const int n = blockIdx.x * 512 + threadIdx.x;
    if (n >= N) return;
    float wstart, hstart, sub_w, sub_h;
    {
#pragma clang fp contract(off)
        const float inv_stride = 0.0625f;
        float rsw = rois[n * 5 + 1] * inv_stride;
        float rsh = rois[n * 5 + 2] * inv_stride;
        float rew = rois[n * 5 + 3] * inv_stride;
        float reh = rois[n * 5 + 4] * inv_stride;
        float roi_h = reh - rsh; if (!(roi_h > 0.1f)) roi_h = 0.1f;
        float roi_w = rew - rsw; if (!(roi_w > 0.1f)) roi_w = 0.1f;
        float bin_h = roi_h / 7.0f;
        float bin_w = roi_w / 7.0f;
        sub_h = bin_h * 0.25f;
        sub_w = bin_w * 0.25f;
        hstart = floorf(rsh + (float)ph * bin_h);
        wstart = floorf(rsw + (float)pw * bin_w);
    }
    float Xw0=0.f,Xw1=0.f,Xw2=0.f,Xw3=0.f,cntx=0.f;
    float Yw0=0.f,Yw1=0.f,Yw2=0.f,Yw3=0.f,cnty=0.f;
    int xbase = 0, ybase = 0;
#pragma unroll
    for (int iw = 0; iw < 4; ++iw) {
        float w;
        {
#pragma clang fp contract(off)
            w = wstart + ((float)iw + 0.5f) * sub_w;
        }
        float kw  = (w > -1.0f && w < 34.0f) ? 1.0f : 0.0f;
        float x1f = floorf(w), x2f = ceilf(w);
        float x1v = (x1f >= 0.0f && x1f < 34.0f) ? 1.0f : 0.0f;
        float x2v = (x2f >= 0.0f && x2f < 34.0f) ? 1.0f : 0.0f;
        int x1 = (int)fminf(fmaxf(x1f, 0.0f), 33.0f);
        int x2 = (int)fminf(fmaxf(x2f, 0.0f), 33.0f);
        float dx = w - (float)x1;
        if (iw == 0) xbase = x1;
        float a = kw * (1.0f - dx) * x1v;
        float b = kw * dx * x2v;
        int i1 = x1 - xbase, i2 = x2 - xbase;
        Xw0 += (i1==0)?a:0.f; Xw1 += (i1==1)?a:0.f; Xw2 += (i1==2)?a:0.f; Xw3 += (i1==3)?a:0.f;
        Xw0 += (i2==0)?b:0.f; Xw1 += (i2==1)?b:0.f; Xw2 += (i2==2)?b:0.f; Xw3 += (i2==3)?b:0.f;
        cntx += kw;
    }
#pragma unroll
    for (int ih = 0; ih < 4; ++ih) {
        float h;
        {
#pragma clang fp contract(off)
            h = hstart + ((float)ih + 0.5f) * sub_h;
        }
        float kh  = (h > -1.0f && h < 34.0f) ? 1.0f : 0.0f;
        float y1f = floorf(h), y2f = ceilf(h);
        float y1v = (y1f >= 0.0f && y1f < 34.0f) ? 1.0f : 0.0f;
        float y2v = (y2f >= 0.0f && y2f < 34.0f) ? 1.0f : 0.0f;
        int y1 = (int)fminf(fmaxf(y1f, 0.0f), 33.0f);
        int y2 = (int)fminf(fmaxf(y2f, 0.0f), 33.0f);
        float dy = h - (float)y1;
        if (ih == 0) ybase = y1;
        float a = kh * (1.0f - dy) * y1v;
        float b = kh * dy * y2v;
        int i1 = y1 - ybase, i2 = y2 - ybase;
        Yw0 += (i1==0)?a:0.f; Yw1 += (i1==1)?a:0.f; Yw2 += (i1==2)?a:0.f; Yw3 += (i1==3)?a:0.f;
        Yw0 += (i2==0)?b:0.f; Yw1 += (i2==1)?b:0.f; Yw2 += (i2==2)?b:0.f; Yw3 += (i2==3)?b:0.f;
        cnty += kh;
    }
    float4 v0s = {0,0,0,0}, v1s = {0,0,0,0};
    float2 v2s = {0,0};
#pragma unroll
    for (int cy = 0; cy < 4; ++cy) {
        float wy = (cy==0)?Yw0:(cy==1)?Yw1:(cy==2)?Yw2:Yw3;
        if (wy != 0.0f) {
            int yy = min(ybase + cy, 33);
            const float* rowp = &tile[yy * (W * CPAD)];
#pragma unroll
            for (int cx = 0; cx < 4; ++cx) {
                float wx = (cx==0)?Xw0:(cx==1)?Xw1:(cx==2)?Xw2:Xw3;
                float wgt = wy * wx;
                if (wgt != 0.0f) {
                    int xx = min(xbase + cx, 33);
                    const float* t = rowp + xx * CPAD;
                    float4 a = *(const float4*)(t);
                    float4 b = *(const float4*)(t + 4);
                    float2 c2 = *(const float2*)(t + 8);
                    v0s.x += wgt*a.x; v0s.y += wgt*a.y; v0s.z += wgt*a.z; v0s.w += wgt*a.w;
                    v1s.x += wgt*b.x; v1s.y += wgt*b.y; v1s.z += wgt*b.z; v1s.w += wgt*b.w;
                    v2s.x += wgt*c2.x; v2s.y += wgt*c2.y;
                }
            }
        }
    }
    float cnt = cntx * cnty;
    if (!(cnt > 0.0f)) cnt = 1.0f;
    float inv = 1.0f / cnt;
    float r[10] = { v0s.x*inv, v0s.y*inv, v0s.z*inv, v0s.w*inv,
                    v1s.x*inv, v1s.y*inv, v1s.z*inv, v1s.w*inv,
                    v2s.x*inv, v2s.y*inv };
    float* __restrict__ o = dst + (size_t)n * R + p;
#pragma unroll
    for (int c = 0; c < C; ++c) o[c * P] = r[c];
}

extern "C" void kernel_launch(void* const* d_in, const int* in_sizes, int n_in,
                              void* d_out, int out_size, void* d_ws, size_t ws_size,
                              hipStream_t stream) {
    const float* ft   = (const float*)d_in[0];
    const float* rois = (const float*)d_in[1];
    float* out = (float*)d_out;
    const int N = in_sizes[1] / 5;

    const size_t szA   = (size_t)P * HW * sizeof(uint4);     // 906,304 B
    const size_t offB  = (szA + 255) & ~(size_t)255;
    const size_t szB   = (size_t)P * HW * sizeof(unsigned);  // 226,576 B
    const size_t wsOff = (offB + szB + 255) & ~(size_t)255;
    const size_t need  = wsOff + (size_t)RU * N * sizeof(unsigned); // +16 MB
    if (d_ws != nullptr && ws_size >= need && (N % 64) == 0) {
        uint4*    ftA  = (uint4*)d_ws;
        unsigned* ftBb = (unsigned*)((char*)d_ws + offB);
        unsigned* ws2  = (unsigned*)((char*)d_ws + wsOff);
        dfmb_pack<<<dim3(P, (HW + 255) / 256), dim3(256), 0, stream>>>(ft, ftA, ftBb);
        dfmb_main<<<dim3((N + 511) / 512, P), dim3(512), 0, stream>>>(ftA, ftBb, rois, ws2, N);
        dfmb_phase2<<<dim3(N / 64), dim3(1024), 0, stream>>>(ws2, out, N);
    } else {
        dim3 grid1((N + 511) / 512, P);
        dfmb_phase1_direct<<<grid1, dim3(512), 0, stream>>>(ft, rois, out, N);
    }
}

// Round 2
// 93.524 us; speedup vs baseline: 1.0286x; 1.0076x over previous
//
#include <hip/hip_runtime.h>

// DFMBPSROIAlign. R12 (= R11 + pack fused into main):
//  - dfmb_pack deleted. Main stages its (p) slice DIRECTLY from fp32 ft,
//    converting to bf16 in-flight into the same split slabs:
//      slabA[pix] = uint4 (ch0..7, 16B/pixel) -> ds_read_b128
//      slabB[pix] = uint  (ch8..9,  4B/pixel) -> ds_read_b32
//    Staging bytes/block 23->46KB (L2/L3-resident; +~1us aggregate), but
//    one dispatch + launch gap + 1.13MB ws round-trip deleted. cvt cost
//    ~70 VALU/thread, hidden under stage loads.
//  - R11's bank-spread kept: 16B pixel stride => b128 start slot pix&7
//    covers all 32 banks; b32 at bank pix%32 (2-way aliasing = free).
//  Structure otherwise proven R6-R11: per-part LDS slab gather with
//  separable <=4x<=4 footprint, bf16-pair blocked ws, 64n-slab
//  transpose+unpack (phase2), NT stores. Harness poison floor ~47-56us.

constexpr int C  = 10;
constexpr int PH = 7;
constexpr int PW = 7;
constexpr int H  = 34;
constexpr int W  = 34;
constexpr int P  = PH * PW;         // 49
constexpr int HW = H * W;           // 1156
constexpr int FT_C_STRIDE = P * HW; // 56644
constexpr int CPAD = 12;            // fp32 fallback pad
constexpr int R  = C * P;           // 490
constexpr int RU = (C / 2) * P;     // 245 uint rows (bf16 channel pairs)

typedef float vf2 __attribute__((ext_vector_type(2)));  // native vec for NT store

__device__ inline unsigned bf16rn(float f) {
    unsigned u = __float_as_uint(f);
    return (u + 0x7FFFu + ((u >> 16) & 1u)) >> 16;
}
__device__ inline float bf16lo(unsigned u) { return __uint_as_float(u << 16); }
__device__ inline float bf16hi(unsigned u) { return __uint_as_float(u & 0xFFFF0000u); }

// ---- main: stage fp32 ft -> bf16 LDS slabs in-flight, gather, ws out ----
__global__ __launch_bounds__(512) void dfmb_main(
    const float* __restrict__ ft,
    const float* __restrict__ rois,
    unsigned* __restrict__ ws,  // [n/64][c2*49+p][n%64] bf16 pairs
    int N)
{
    __shared__ uint4 slabA[HW];                   // 18496 B, 16B/pixel
    __shared__ __align__(16) unsigned slabB[HW];  //  4624 B,  4B/pixel

    const int p  = blockIdx.y;
    const int ph = p / PW;
    const int pw = p - ph * PW;

    // Stage + convert: 10 coalesced dword streams per pixel round.
    {
        const float* __restrict__ src = ft + p * HW;
        for (int pix = threadIdx.x; pix < HW; pix += 512) {
            unsigned d[5];
#pragma unroll
            for (int k = 0; k < 5; ++k) {
                float a = src[(2 * k) * FT_C_STRIDE + pix];
                float b = src[(2 * k + 1) * FT_C_STRIDE + pix];
                d[k] = bf16rn(a) | (bf16rn(b) << 16);
            }
            slabA[pix] = make_uint4(d[0], d[1], d[2], d[3]);
            slabB[pix] = d[4];
        }
    }
    __syncthreads();

    const int n = blockIdx.x * 512 + threadIdx.x;
    if (n >= N) return;

    // Coordinate setup — contraction OFF so floor() args match the reference
    // rounding (verified passing R0-R11).
    float wstart, hstart, sub_w, sub_h;
    {
#pragma clang fp contract(off)
        const float inv_stride = 0.0625f;
        float rsw = rois[n * 5 + 1] * inv_stride;
        float rsh = rois[n * 5 + 2] * inv_stride;
        float rew = rois[n * 5 + 3] * inv_stride;
        float reh = rois[n * 5 + 4] * inv_stride;
        float roi_h = reh - rsh; if (!(roi_h > 0.1f)) roi_h = 0.1f;
        float roi_w = rew - rsw; if (!(roi_w > 0.1f)) roi_w = 0.1f;
        float bin_h = roi_h / 7.0f;
        float bin_w = roi_w / 7.0f;
        sub_h = bin_h * 0.25f;
        sub_w = bin_w * 0.25f;
        hstart = floorf(rsh + (float)ph * bin_h);
        wstart = floorf(rsw + (float)pw * bin_w);
    }

    // ---- separable 1-D weight footprints (<=4 cols x <=4 rows) ----
    float Xw0 = 0.f, Xw1 = 0.f, Xw2 = 0.f, Xw3 = 0.f, cntx = 0.f;
    int xbase = 0;
#pragma unroll
    for (int iw = 0; iw < 4; ++iw) {
        float w;
        {
#pragma clang fp contract(off)
            w = wstart + ((float)iw + 0.5f) * sub_w;
        }
        float kw  = (w > -1.0f && w < 34.0f) ? 1.0f : 0.0f;
        float x1f = floorf(w), x2f = ceilf(w);
        float x1v = (x1f >= 0.0f && x1f < 34.0f) ? 1.0f : 0.0f;
        float x2v = (x2f >= 0.0f && x2f < 34.0f) ? 1.0f : 0.0f;
        int x1 = (int)fminf(fmaxf(x1f, 0.0f), 33.0f);
        int x2 = (int)fminf(fmaxf(x2f, 0.0f), 33.0f);
        float dx = w - (float)x1;           // vs CLAMPED corner (ref semantics)
        if (iw == 0) xbase = x1;            // minimal column (w monotone in iw)
        float a = kw * (1.0f - dx) * x1v;
        float b = kw * dx * x2v;
        int i1 = x1 - xbase, i2 = x2 - xbase;
        Xw0 += (i1 == 0) ? a : 0.f;  Xw1 += (i1 == 1) ? a : 0.f;
        Xw2 += (i1 == 2) ? a : 0.f;  Xw3 += (i1 == 3) ? a : 0.f;
        Xw0 += (i2 == 0) ? b : 0.f;  Xw1 += (i2 == 1) ? b : 0.f;
        Xw2 += (i2 == 2) ? b : 0.f;  Xw3 += (i2 == 3) ? b : 0.f;
        cntx += kw;
    }

    float Yw0 = 0.f, Yw1 = 0.f, Yw2 = 0.f, Yw3 = 0.f, cnty = 0.f;
    int ybase = 0;
#pragma unroll
    for (int ih = 0; ih < 4; ++ih) {
        float h;
        {
#pragma clang fp contract(off)
            h = hstart + ((float)ih + 0.5f) * sub_h;
        }
        float kh  = (h > -1.0f && h < 34.0f) ? 1.0f : 0.0f;
        float y1f = floorf(h), y2f = ceilf(h);
        float y1v = (y1f >= 0.0f && y1f < 34.0f) ? 1.0f : 0.0f;
        float y2v = (y2f >= 0.0f && y2f < 34.0f) ? 1.0f : 0.0f;
        int y1 = (int)fminf(fmaxf(y1f, 0.0f), 33.0f);
        int y2 = (int)fminf(fmaxf(y2f, 0.0f), 33.0f);
        float dy = h - (float)y1;
        if (ih == 0) ybase = y1;
        float a = kh * (1.0f - dy) * y1v;
        float b = kh * dy * y2v;
        int i1 = y1 - ybase, i2 = y2 - ybase;
        Yw0 += (i1 == 0) ? a : 0.f;  Yw1 += (i1 == 1) ? a : 0.f;
        Yw2 += (i1 == 2) ? a : 0.f;  Yw3 += (i1 == 3) ? a : 0.f;
        Yw0 += (i2 == 0) ? b : 0.f;  Yw1 += (i2 == 1) ? b : 0.f;
        Yw2 += (i2 == 2) ? b : 0.f;  Yw3 += (i2 == 3) ? b : 0.f;
        cnty += kh;
    }

    // ---- accumulate over footprint: b128 (ch0..7) + b32 (ch8..9) ----
    float s0=0.f,s1=0.f,s2=0.f,s3=0.f,s4=0.f,s5=0.f,s6=0.f,s7=0.f,s8=0.f,s9=0.f;
#pragma unroll
    for (int cy = 0; cy < 4; ++cy) {
        float wy = (cy == 0) ? Yw0 : (cy == 1) ? Yw1 : (cy == 2) ? Yw2 : Yw3;
        if (wy != 0.0f) {
            int yy = min(ybase + cy, 33);
            int rowoff = yy * W;
#pragma unroll
            for (int cx = 0; cx < 4; ++cx) {
                float wx = (cx == 0) ? Xw0 : (cx == 1) ? Xw1
                         : (cx == 2) ? Xw2 : Xw3;
                float wgt = wy * wx;
                if (wgt != 0.0f) {
                    int xx = min(xbase + cx, 33);
                    int pixi = rowoff + xx;
                    uint4 a = slabA[pixi];      // ch 0..7
                    unsigned b = slabB[pixi];   // ch 8..9
                    s0 += wgt * bf16lo(a.x);  s1 += wgt * bf16hi(a.x);
                    s2 += wgt * bf16lo(a.y);  s3 += wgt * bf16hi(a.y);
                    s4 += wgt * bf16lo(a.z);  s5 += wgt * bf16hi(a.z);
                    s6 += wgt * bf16lo(a.w);  s7 += wgt * bf16hi(a.w);
                    s8 += wgt * bf16lo(b);    s9 += wgt * bf16hi(b);
                }
            }
        }
    }

    float cnt = cntx * cnty;
    if (!(cnt > 0.0f)) cnt = 1.0f;
    float inv = 1.0f / cnt;

    // Pack 10 results into 5 bf16-pair uints; blocked coalesced stores.
    unsigned r01 = bf16rn(s0 * inv) | (bf16rn(s1 * inv) << 16);
    unsigned r23 = bf16rn(s2 * inv) | (bf16rn(s3 * inv) << 16);
    unsigned r45 = bf16rn(s4 * inv) | (bf16rn(s5 * inv) << 16);
    unsigned r67 = bf16rn(s6 * inv) | (bf16rn(s7 * inv) << 16);
    unsigned r89 = bf16rn(s8 * inv) | (bf16rn(s9 * inv) << 16);

    unsigned* __restrict__ o = ws + (size_t)(n >> 6) * (RU * 64)
                                  + (size_t)p * 64 + (n & 63);
    o[0 * (P * 64)] = r01;
    o[1 * (P * 64)] = r23;
    o[2 * (P * 64)] = r45;
    o[3 * (P * 64)] = r67;
    o[4 * (P * 64)] = r89;
}

// Per-64n-slab transpose+unpack: ws[nblk][c2*49+p][nl] (245x64 uints,
// contiguous 62.7KB) -> out[n][c*49+p] fp32, nontemporal vf2 stores.
__global__ __launch_bounds__(1024) void dfmb_phase2(
    const unsigned* __restrict__ ws, float* __restrict__ out, int N)
{
    __shared__ unsigned t[RU * 65];     // 63700 B
    const int nblk = blockIdx.x;
    const unsigned* __restrict__ srcb = ws + (size_t)nblk * (RU * 64);

    // Load 245 rows x 64 nl contiguous via uint4 (3920 of them).
    for (int i = threadIdx.x; i < RU * 16; i += 1024) {
        int rr  = i >> 4;
        int nl4 = (i & 15) * 4;
        uint4 v = ((const uint4*)srcb)[i];
        unsigned* tp = &t[rr * 65 + nl4];
        tp[0] = v.x; tp[1] = v.y; tp[2] = v.z; tp[3] = v.w;
    }
    __syncthreads();

    // Write out[n0+nl][2k..2k+1]: lane-consecutive k -> coalesced 512B vf2.
    const int n0 = nblk * 64;
    for (int j = threadIdx.x; j < 64 * (R / 2); j += 1024) {
        int nl = j / (R / 2);
        int k  = j - nl * (R / 2);
        int r0 = 2 * k, r1 = 2 * k + 1;
        int c0 = r0 / P, p0 = r0 - c0 * P;
        int c1 = r1 / P, p1 = r1 - c1 * P;
        unsigned u0 = t[((c0 >> 1) * P + p0) * 65 + nl];
        unsigned u1 = t[((c1 >> 1) * P + p1) * 65 + nl];
        vf2 v;
        v.x = (c0 & 1) ? bf16hi(u0) : bf16lo(u0);
        v.y = (c1 & 1) ? bf16hi(u1) : bf16lo(u1);
        __builtin_nontemporal_store(v, (vf2*)(out + (size_t)(n0 + nl) * R) + k);
    }
}

// ---- fallback (no ws): fp32 LDS-slab kernel, direct strided writes ----
__global__ __launch_bounds__(512, 4) void dfmb_phase1_direct(
    const float* __restrict__ ft,
    const float* __restrict__ rois,
    float* __restrict__ dst,
    int N)
{
    __shared__ float tile[HW * CPAD];
    const int p  = blockIdx.y;
    const int ph = p / PW;
    const int pw = p - ph * PW;
    const float* __restrict__ src = ft + p * HW;
    for (int i = threadIdx.x; i < C * HW; i += 512) {
        int c = i / HW;
        int r = i - c * HW;
        tile[r * CPAD + c] = src[c * FT_C_STRIDE + r];
    }
    __syncthreads();
    const int n = blockIdx.x * 512 + threadIdx.x;
    if (n >= N) return;
    float wstart, hstart, sub_w, sub_h;
    {
#pragma clang fp contract(off)
        const float inv_stride = 0.0625f;
        float rsw = rois[n * 5 + 1] * inv_stride;
        float rsh = rois[n * 5 + 2] * inv_stride;
        float rew = rois[n * 5 + 3] * inv_stride;
        float reh = rois[n * 5 + 4] * inv_stride;
        float roi_h = reh - rsh; if (!(roi_h > 0.1f)) roi_h = 0.1f;
        float roi_w = rew - rsw; if (!(roi_w > 0.1f)) roi_w = 0.1f;
        float bin_h = roi_h / 7.0f;
        float bin_w = roi_w / 7.0f;
        sub_h = bin_h * 0.25f;
        sub_w = bin_w * 0.25f;
        hstart = floorf(rsh + (float)ph * bin_h);
        wstart = floorf(rsw + (float)pw * bin_w);
    }
    float Xw0=0.f,Xw1=0.f,Xw2=0.f,Xw3=0.f,cntx=0.f;
    float Yw0=0.f,Yw1=0.f,Yw2=0.f,Yw3=0.f,cnty=0.f;
    int xbase = 0, ybase = 0;
#pragma unroll
    for (int iw = 0; iw < 4; ++iw) {
        float w;
        {
#pragma clang fp contract(off)
            w = wstart + ((float)iw + 0.5f) * sub_w;
        }
        float kw  = (w > -1.0f && w < 34.0f) ? 1.0f : 0.0f;
        float x1f = floorf(w), x2f = ceilf(w);
        float x1v = (x1f >= 0.0f && x1f < 34.0f) ? 1.0f : 0.0f;
        float x2v = (x2f >= 0.0f && x2f < 34.0f) ? 1.0f : 0.0f;
        int x1 = (int)fminf(fmaxf(x1f, 0.0f), 33.0f);
        int x2 = (int)fminf(fmaxf(x2f, 0.0f), 33.0f);
        float dx = w - (float)x1;
        if (iw == 0) xbase = x1;
        float a = kw * (1.0f - dx) * x1v;
        float b = kw * dx * x2v;
        int i1 = x1 - xbase, i2 = x2 - xbase;
        Xw0 += (i1==0)?a:0.f; Xw1 += (i1==1)?a:0.f; Xw2 += (i1==2)?a:0.f; Xw3 += (i1==3)?a:0.f;
        Xw0 += (i2==0)?b:0.f; Xw1 += (i2==1)?b:0.f; Xw2 += (i2==2)?b:0.f; Xw3 += (i2==3)?b:0.f;
        cntx += kw;
    }
#pragma unroll
    for (int ih = 0; ih < 4; ++ih) {
        float h;
        {
#pragma clang fp contract(off)
            h = hstart + ((float)ih + 0.5f) * sub_h;
        }
        float kh  = (h > -1.0f && h < 34.0f) ? 1.0f : 0.0f;
        float y1f = floorf(h), y2f = ceilf(h);
        float y1v = (y1f >= 0.0f && y1f < 34.0f) ? 1.0f : 0.0f;
        float y2v = (y2f >= 0.0f && y2f < 34.0f) ? 1.0f : 0.0f;
        int y1 = (int)fminf(fmaxf(y1f, 0.0f), 33.0f);
        int y2 = (int)fminf(fmaxf(y2f, 0.0f), 33.0f);
        float dy = h - (float)y1;
        if (ih == 0) ybase = y1;
        float a = kh * (1.0f - dy) * y1v;
        float b = kh * dy * y2v;
        int i1 = y1 - ybase, i2 = y2 - ybase;
        Yw0 += (i1==0)?a:0.f; Yw1 += (i1==1)?a:0.f; Yw2 += (i1==2)?a:0.f; Yw3 += (i1==3)?a:0.f;
        Yw0 += (i2==0)?b:0.f; Yw1 += (i2==1)?b:0.f; Yw2 += (i2==2)?b:0.f; Yw3 += (i2==3)?b:0.f;
        cnty += kh;
    }
    float4 v0s = {0,0,0,0}, v1s = {0,0,0,0};
    float2 v2s = {0,0};
#pragma unroll
    for (int cy = 0; cy < 4; ++cy) {
        float wy = (cy==0)?Yw0:(cy==1)?Yw1:(cy==2)?Yw2:Yw3;
        if (wy != 0.0f) {
            int yy = min(ybase + cy, 33);
            const float* rowp = &tile[yy * (W * CPAD)];
#pragma unroll
            for (int cx = 0; cx < 4; ++cx) {
                float wx = (cx==0)?Xw0:(cx==1)?Xw1:(cx==2)?Xw2:Xw3;
                float wgt = wy * wx;
                if (wgt != 0.0f) {
                    int xx = min(xbase + cx, 33);
                    const float* t = rowp + xx * CPAD;
                    float4 a = *(const float4*)(t);
                    float4 b = *(const float4*)(t + 4);
                    float2 c2 = *(const float2*)(t + 8);
                    v0s.x += wgt*a.x; v0s.y += wgt*a.y; v0s.z += wgt*a.z; v0s.w += wgt*a.w;
                    v1s.x += wgt*b.x; v1s.y += wgt*b.y; v1s.z += wgt*b.z; v1s.w += wgt*b.w;
                    v2s.x += wgt*c2.x; v2s.y += wgt*c2.y;
                }
            }
        }
    }
    float cnt = cntx * cnty;
    if (!(cnt > 0.0f)) cnt = 1.0f;
    float inv = 1.0f / cnt;
    float r[10] = { v0s.x*inv, v0s.y*inv, v0s.z*inv, v0s.w*inv,
                    v1s.x*inv, v1s.y*inv, v1s.z*inv, v1s.w*inv,
                    v2s.x*inv, v2s.y*inv };
    float* __restrict__ o = dst + (size_t)n * R + p;
#pragma unroll
    for (int c = 0; c < C; ++c) o[c * P] = r[c];
}

extern "C" void kernel_launch(void* const* d_in, const int* in_sizes, int n_in,
                              void* d_out, int out_size, void* d_ws, size_t ws_size,
                              hipStream_t stream) {
    const float* ft   = (const float*)d_in[0];
    const float* rois = (const float*)d_in[1];
    float* out = (float*)d_out;
    const int N = in_sizes[1] / 5;

    const size_t need = (size_t)RU * N * sizeof(unsigned); // ~16 MB
    if (d_ws != nullptr && ws_size >= need && (N % 64) == 0) {
        unsigned* ws2 = (unsigned*)d_ws;
        dfmb_main<<<dim3((N + 511) / 512, P), dim3(512), 0, stream>>>(ft, rois, ws2, N);
        dfmb_phase2<<<dim3(N / 64), dim3(1024), 0, stream>>>(ws2, out, N);
    } else {
        dim3 grid1((N + 511) / 512, P);
        dfmb_phase1_direct<<<grid1, dim3(512), 0, stream>>>(ft, rois, out, N);
    }
}